// Round 6
// baseline (350.292 us; speedup 1.0000x reference)
//
#include <hip/hip_runtime.h>
#include <hip/hip_cooperative_groups.h>
#include <math.h>

namespace cg = cooperative_groups;

#define B_ 2
#define N_ 4100
#define C_ 768
#define T_ 4
#define H_ 12
#define D_ 64
#define M_ 4096
#define S_ 48          // T_*H_
#define KS_ 6          // k-split for score GEMM
#define KC_ 128        // channels per k-split chunk (2 sub-chunks of 64)
#define GRID_ 768      // 64 mtiles * B_ * KS_
#define SCALE 0.125f   // d^-0.5 = 1/8

// ---- top-2 helpers (ties -> lowest index, matching jax.lax.top_k) ----
__device__ __forceinline__ bool better(float va, int ia, float vb, int ib) {
  return (va > vb) || (va == vb && ia < ib);
}

__device__ __forceinline__ void merge2(float& v1, int& i1, float& v2, int& i2,
                                       float ov1, int oi1, float ov2, int oi2) {
  if (better(ov1, oi1, v1, i1)) {
    float tv; int ti;
    tv = v1; ti = i1; v1 = ov1; i1 = oi1; ov1 = tv; oi1 = ti;
    tv = v2; ti = i2; v2 = ov2; i2 = oi2; ov2 = tv; oi2 = ti;
  }
  if (better(ov1, oi1, v2, i2)) { v2 = ov1; i2 = oi1; }
}

// ---- K1 (normal dispatch): blocks 0..95 compute qk; 96..767 zero d_out.
// Dispatch boundary guarantees qk/zero visibility for the next kernel.
__global__ __launch_bounds__(256) void qkzero_kernel(const float* __restrict__ x,
    const float* __restrict__ qs_w, const float* __restrict__ kv_w,
    float* __restrict__ qk, float* __restrict__ out) {
  const int blk = blockIdx.x;
  const int tid = threadIdx.x;
  if (blk < B_ * S_) {
    const int h = blk % H_;
    const int t = (blk / H_) % T_;
    const int b = blk / S_;
    __shared__ float xs[C_];
    __shared__ float red[256];
    __shared__ float qseg[D_];
    for (int i = tid; i < C_; i += 256) xs[i] = x[((size_t)b * N_ + t) * C_ + i];
    __syncthreads();
    {
      const int j = tid & 63;
      const int pt = tid >> 6;          // 4 parts of 192 channels
      const float* wr = qs_w + ((size_t)t * C_ + h * D_ + j) * C_ + pt * 192;
      float a = 0.f;
      for (int c = 0; c < 192; ++c) a += xs[pt * 192 + c] * wr[c];
      red[tid] = a;
    }
    __syncthreads();
    if (tid < 64)
      qseg[tid] = (red[tid] + red[tid + 64] + red[tid + 128] + red[tid + 192]) * SCALE;
    __syncthreads();
    for (int c = tid; c < C_; c += 256) {
      float a = 0.f;
      #pragma unroll 8
      for (int j = 0; j < 64; ++j) a += qseg[j] * kv_w[((size_t)(h * D_ + j)) * C_ + c];
      qk[(size_t)blk * C_ + c] = a;
    }
  } else {
    const int zb = blk - B_ * S_;
    const int NV4 = (B_ * N_ * C_) / 4;        // 1,574,400 float4s
    float4 z = make_float4(0.f, 0.f, 0.f, 0.f);
    float4* ov = (float4*)out;
    for (int i = zb * 256 + tid; i < NV4; i += (GRID_ - B_ * S_) * 256) ov[i] = z;
  }
}

// ---- score phase body: one (b, mtile, kc) tile per block ----
__device__ __forceinline__ void score_body(int blk, int tid, const float* __restrict__ x,
    const float* __restrict__ qk, float* __restrict__ part, float* smem) {
  const int mt = blk & 63;
  const int b = (blk >> 6) & 1;
  const int kc = blk >> 7;          // 0..5
  const int m0 = mt * 64;
  float (*fbuf)[68] = (float(*)[68])smem;              // 64 x 68
  float (*qkbuf)[68] = (float(*)[68])(smem + 64 * 68); // 48 x 68
  const int mg = tid & 15;   // m rows: mg + 16u
  const int sg = tid >> 4;   // s cols: sg*3 + i

  float acc[4][3];
  #pragma unroll
  for (int u = 0; u < 4; ++u)
    #pragma unroll
    for (int i = 0; i < 3; ++i) acc[u][i] = 0.f;

  const float* xb = x + ((size_t)b * N_ + T_ + m0) * C_ + kc * KC_;
  const float* qkb = qk + (size_t)b * S_ * C_ + kc * KC_;

  for (int cc = 0; cc < KC_ / 64; ++cc) {
    __syncthreads();
    for (int i = tid; i < 64 * 16; i += 256) {
      int row = i >> 4, c4 = i & 15;
      *(float4*)&fbuf[row][c4 * 4] =
          *(const float4*)(xb + (size_t)row * C_ + cc * 64 + c4 * 4);
    }
    for (int i = tid; i < 48 * 16; i += 256) {
      int s = i >> 4, c4 = i & 15;
      *(float4*)&qkbuf[s][c4 * 4] =
          *(const float4*)(qkb + (size_t)s * C_ + cc * 64 + c4 * 4);
    }
    __syncthreads();
    #pragma unroll 4
    for (int c4 = 0; c4 < 16; ++c4) {
      float4 f[4], q[3];
      f[0] = *(const float4*)&fbuf[mg][c4 * 4];
      f[1] = *(const float4*)&fbuf[mg + 16][c4 * 4];
      f[2] = *(const float4*)&fbuf[mg + 32][c4 * 4];
      f[3] = *(const float4*)&fbuf[mg + 48][c4 * 4];
      q[0] = *(const float4*)&qkbuf[sg * 3 + 0][c4 * 4];
      q[1] = *(const float4*)&qkbuf[sg * 3 + 1][c4 * 4];
      q[2] = *(const float4*)&qkbuf[sg * 3 + 2][c4 * 4];
      #pragma unroll
      for (int u = 0; u < 4; ++u)
        #pragma unroll
        for (int i = 0; i < 3; ++i)
          acc[u][i] += f[u].x * q[i].x + f[u].y * q[i].y +
                       f[u].z * q[i].z + f[u].w * q[i].w;
    }
  }

  #pragma unroll
  for (int i = 0; i < 3; ++i) {
    int s = sg * 3 + i;
    float* pp = part + (((size_t)kc * B_ + b) * S_ + s) * M_ + m0 + mg;
    #pragma unroll
    for (int u = 0; u < 4; ++u) pp[16 * u] = acc[u][i];
  }
}

// ---- gather phase body: blocks 0..95 only. k-sum + top-2 + v-proj + scatter ----
__device__ __forceinline__ void gather_body(int blk, int tid, const float* __restrict__ x,
    const float* __restrict__ kv_w, const float* __restrict__ experts_w,
    const float* __restrict__ part, float* __restrict__ out, float* smem) {
  const int h = blk % H_;
  const int t = (blk / H_) % T_;
  const int b = blk / S_;
  float* f0 = smem;              // 768
  float* f1 = smem + 768;        // 768
  float* fc = smem + 1536;       // 768
  float* red = smem + 2304;      // 256
  float* attnh = smem + 2560;    // 64
  float* sel = smem + 2624;      // 4
  float (*cbuf)[4] = (float(*)[4])(smem + 2640);  // 4x4
  __syncthreads();

  // --- k-sum over KS_ partials + local top-2; 4 float4 passes of 1024 m ---
  float v1 = -INFINITY, v2 = -INFINITY;
  int i1 = 0x7fffffff, i2 = 0x7fffffff;
  const float* p0 = part + (size_t)blk * M_;      // (b*S+s) == blk
  const size_t kstride = (size_t)B_ * S_ * M_;
  #pragma unroll
  for (int ii = 0; ii < 4; ++ii) {
    const int m = ii * 1024 + tid * 4;
    float4 a = make_float4(0.f, 0.f, 0.f, 0.f);
    #pragma unroll
    for (int kc = 0; kc < KS_; ++kc) {
      float4 v = *(const float4*)(p0 + kc * kstride + m);
      a.x += v.x; a.y += v.y; a.z += v.z; a.w += v.w;
    }
    const float av[4] = {a.x, a.y, a.z, a.w};
    #pragma unroll
    for (int c = 0; c < 4; ++c) {
      if (better(av[c], m + c, v1, i1)) { v2 = v1; i2 = i1; v1 = av[c]; i1 = m + c; }
      else if (better(av[c], m + c, v2, i2)) { v2 = av[c]; i2 = m + c; }
    }
  }
  #pragma unroll
  for (int off = 1; off < 64; off <<= 1) {
    float ov1 = __shfl_xor(v1, off);
    int   oi1 = __shfl_xor(i1, off);
    float ov2 = __shfl_xor(v2, off);
    int   oi2 = __shfl_xor(i2, off);
    merge2(v1, i1, v2, i2, ov1, oi1, ov2, oi2);
  }
  const int w = tid >> 6, lane = tid & 63;
  if (lane == 0) {
    cbuf[w][0] = v1; ((int*)cbuf[w])[1] = i1;
    cbuf[w][2] = v2; ((int*)cbuf[w])[3] = i2;
  }
  __syncthreads();
  if (tid == 0) {
    for (int ww = 1; ww < 4; ++ww)
      merge2(v1, i1, v2, i2, cbuf[ww][0], ((int*)cbuf[ww])[1],
             cbuf[ww][2], ((int*)cbuf[ww])[3]);
    float w1 = 1.f / (1.f + expf(v2 - v1));
    ((int*)sel)[0] = i1; ((int*)sel)[1] = i2;
    sel[2] = w1; sel[3] = 1.f - w1;
  }
  __syncthreads();
  const int s1 = ((const int*)sel)[0];
  const int s2 = ((const int*)sel)[1];
  const float w1 = sel[2], w2 = sel[3];

  // --- load selected feature rows ---
  const float* r0 = x + ((size_t)b * N_ + T_ + s1) * C_;
  const float* r1 = x + ((size_t)b * N_ + T_ + s2) * C_;
  for (int i = tid; i < C_; i += 256) {
    float a = r0[i], bb = r1[i];
    f0[i] = a; f1[i] = bb; fc[i] = w1 * a + w2 * bb;
  }
  __syncthreads();

  // --- v-projection on combined row -> attnh[64] ---
  const int j = tid & 63, pt = tid >> 6;
  {
    const float* kr = kv_w + ((size_t)(C_ + h * D_ + j)) * C_ + pt * 192;
    float a = 0.f;
    for (int c = 0; c < 192; ++c) a += fc[pt * 192 + c] * kr[c];
    red[tid] = a;
  }
  __syncthreads();
  if (tid < 64)
    attnh[tid] = red[tid] + red[tid + 64] + red[tid + 128] + red[tid + 192];
  __syncthreads();

  // --- token + feature scatter (shared experts_w slice) ---
  const size_t ot = ((size_t)b * N_ + t) * C_;
  const size_t o0 = ((size_t)b * N_ + T_ + s1) * C_;
  const size_t o1 = ((size_t)b * N_ + T_ + s2) * C_;
  for (int o = tid; o < C_; o += 256) {
    const float* er = experts_w + ((size_t)t * C_ + o) * C_ + h * D_;
    float at = 0.f, a0 = 0.f, a1 = 0.f;
    #pragma unroll 8
    for (int c = 0; c < D_; ++c) {
      float e = er[c];
      at += e * attnh[c];
      a0 += e * f0[h * D_ + c];
      a1 += e * f1[h * D_ + c];
    }
    atomicAdd(&out[ot + o], at);
    atomicAdd(&out[o0 + o], w1 * a0);
    atomicAdd(&out[o1 + o], w2 * a1);
  }
}

// ---- K2 (cooperative): score -> fenced grid.sync -> gather ----
__global__ __launch_bounds__(256) void coop_kernel(const float* __restrict__ x,
    const float* __restrict__ kv_w, const float* __restrict__ experts_w,
    const float* __restrict__ qk, float* __restrict__ part, float* __restrict__ out) {
  cg::grid_group grid = cg::this_grid();
  __shared__ __align__(16) float smem[7616];   // 30464 B, phase-aliased
  score_body(blockIdx.x, threadIdx.x, x, qk, part, smem);
  __threadfence();   // release: force part writes out of this XCD's L2
  grid.sync();
  __threadfence();   // acquire: invalidate stale L1/L2 lines before part reads
  if (blockIdx.x < B_ * S_)
    gather_body(blockIdx.x, threadIdx.x, x, kv_w, experts_w, part, out, smem);
}

// ---- fallback pair (normal dispatches, identical numerics) ----
__global__ __launch_bounds__(256) void score_only(const float* __restrict__ x,
    const float* __restrict__ qk, float* __restrict__ part) {
  __shared__ __align__(16) float smem[7616];
  score_body(blockIdx.x, threadIdx.x, x, qk, part, smem);
}

__global__ __launch_bounds__(256) void gather_only(const float* __restrict__ x,
    const float* __restrict__ kv_w, const float* __restrict__ experts_w,
    const float* __restrict__ part, float* __restrict__ out) {
  __shared__ __align__(16) float smem[7616];
  gather_body(blockIdx.x, threadIdx.x, x, kv_w, experts_w, part, out, smem);
}

extern "C" void kernel_launch(void* const* d_in, const int* in_sizes, int n_in,
                              void* d_out, int out_size, void* d_ws, size_t ws_size,
                              hipStream_t stream) {
  const float* x         = (const float*)d_in[0];
  const float* qs_w      = (const float*)d_in[1];
  const float* kv_w      = (const float*)d_in[2];
  const float* experts_w = (const float*)d_in[3];
  float* out = (float*)d_out;

  float* qk   = (float*)d_ws;                        // B*S*C    = 73728 floats
  float* part = qk + (size_t)B_ * S_ * C_;           // KS*B*S*M = 2359296 floats

  hipLaunchKernelGGL(qkzero_kernel, dim3(GRID_), dim3(256), 0, stream,
                     x, qs_w, kv_w, qk, out);

  void* args[] = {(void*)&x, (void*)&kv_w, (void*)&experts_w,
                  (void*)&qk, (void*)&part, (void*)&out};
  hipError_t err = hipLaunchCooperativeKernel(
      reinterpret_cast<void*>(coop_kernel), dim3(GRID_), dim3(256), args, 0, stream);
  if (err != hipSuccess) {
    (void)hipGetLastError();   // clear sticky error, take the 2-kernel fallback
    hipLaunchKernelGGL(score_only,  dim3(GRID_),   dim3(256), 0, stream, x, qk, part);
    hipLaunchKernelGGL(gather_only, dim3(B_ * S_), dim3(256), 0, stream,
                       x, kv_w, experts_w, part, out);
  }
}

// Round 7
// 144.264 us; speedup vs baseline: 2.4281x; 2.4281x over previous
//
#include <hip/hip_runtime.h>
#include <math.h>

#define B_ 2
#define N_ 4100
#define C_ 768
#define T_ 4
#define H_ 12
#define D_ 64
#define M_ 4096
#define S_ 48          // T_*H_
#define KS_ 6          // k-split for score GEMM
#define KC_ 128        // channels per k-split chunk (2 sub-chunks of 64)
#define SEG_ 8         // m-segments per (b,s) in reduce
#define GRID_ 768
#define SCALE 0.125f   // d^-0.5 = 1/8

// ---- top-2 helpers (ties -> lowest index, matching jax.lax.top_k) ----
__device__ __forceinline__ bool better(float va, int ia, float vb, int ib) {
  return (va > vb) || (va == vb && ia < ib);
}

__device__ __forceinline__ void merge2(float& v1, int& i1, float& v2, int& i2,
                                       float ov1, int oi1, float ov2, int oi2) {
  if (better(ov1, oi1, v1, i1)) {
    float tv; int ti;
    tv = v1; ti = i1; v1 = ov1; i1 = oi1; ov1 = tv; oi1 = ti;
    tv = v2; ti = i2; v2 = ov2; i2 = oi2; ov2 = tv; oi2 = ti;
  }
  if (better(ov1, oi1, v2, i2)) { v2 = ov1; i2 = oi1; }
}

// ---- K1: blocks 0..95 compute qk; blocks 96..767 zero the whole output.
__global__ __launch_bounds__(256) void qkzero_kernel(const float* __restrict__ x,
    const float* __restrict__ qs_w, const float* __restrict__ kv_w,
    float* __restrict__ qk, float* __restrict__ out) {
  const int blk = blockIdx.x;
  const int tid = threadIdx.x;
  if (blk < B_ * S_) {
    const int h = blk % H_;
    const int t = (blk / H_) % T_;
    const int b = blk / S_;
    __shared__ float xs[C_];
    __shared__ float red[256];
    __shared__ float qseg[D_];
    for (int i = tid; i < C_; i += 256) xs[i] = x[((size_t)b * N_ + t) * C_ + i];
    __syncthreads();
    {
      const int j = tid & 63;
      const int pt = tid >> 6;          // 4 parts of 192 channels
      const float* wr = qs_w + ((size_t)t * C_ + h * D_ + j) * C_ + pt * 192;
      float a = 0.f;
      for (int c = 0; c < 192; ++c) a += xs[pt * 192 + c] * wr[c];
      red[tid] = a;
    }
    __syncthreads();
    if (tid < 64)
      qseg[tid] = (red[tid] + red[tid + 64] + red[tid + 128] + red[tid + 192]) * SCALE;
    __syncthreads();
    for (int c = tid; c < C_; c += 256) {
      float a = 0.f;
      #pragma unroll 8
      for (int j = 0; j < 64; ++j) a += qseg[j] * kv_w[((size_t)(h * D_ + j)) * C_ + c];
      qk[(size_t)blk * C_ + c] = a;
    }
  } else {
    const int zb = blk - B_ * S_;
    const int NV4 = (B_ * N_ * C_) / 4;        // 1,574,400 float4s
    float4 z = make_float4(0.f, 0.f, 0.f, 0.f);
    float4* ov = (float4*)out;
    for (int i = zb * 256 + tid; i < NV4; i += (GRID_ - B_ * S_) * 256) ov[i] = z;
  }
}

// ---- K2: partial scores. block = (b, mtile of 64 m) x (kc of 128 c, 2 stages)
__global__ __launch_bounds__(256) void score_kernel(const float* __restrict__ x,
    const float* __restrict__ qk, float* __restrict__ part) {
  const int mt = blockIdx.x & 63;
  const int b = blockIdx.x >> 6;
  const int kc = blockIdx.y;          // 0..5
  const int tid = threadIdx.x;
  const int m0 = mt * 64;

  __shared__ __align__(16) float fbuf[64][68];
  __shared__ __align__(16) float qkbuf[48][68];

  const int mg = tid & 15;   // m rows: mg + 16u
  const int sg = tid >> 4;   // s cols: sg*3 + i

  float acc[4][3];
  #pragma unroll
  for (int u = 0; u < 4; ++u)
    #pragma unroll
    for (int i = 0; i < 3; ++i) acc[u][i] = 0.f;

  const float* xb = x + ((size_t)b * N_ + T_ + m0) * C_ + kc * KC_;
  const float* qkb = qk + (size_t)b * S_ * C_ + kc * KC_;

  for (int cc = 0; cc < KC_ / 64; ++cc) {
    __syncthreads();
    for (int i = tid; i < 64 * 16; i += 256) {
      int row = i >> 4, c4 = i & 15;
      *(float4*)&fbuf[row][c4 * 4] =
          *(const float4*)(xb + (size_t)row * C_ + cc * 64 + c4 * 4);
    }
    for (int i = tid; i < 48 * 16; i += 256) {
      int s = i >> 4, c4 = i & 15;
      *(float4*)&qkbuf[s][c4 * 4] =
          *(const float4*)(qkb + (size_t)s * C_ + cc * 64 + c4 * 4);
    }
    __syncthreads();
    #pragma unroll 4
    for (int c4 = 0; c4 < 16; ++c4) {
      float4 f[4], q[3];
      f[0] = *(const float4*)&fbuf[mg][c4 * 4];
      f[1] = *(const float4*)&fbuf[mg + 16][c4 * 4];
      f[2] = *(const float4*)&fbuf[mg + 32][c4 * 4];
      f[3] = *(const float4*)&fbuf[mg + 48][c4 * 4];
      q[0] = *(const float4*)&qkbuf[sg * 3 + 0][c4 * 4];
      q[1] = *(const float4*)&qkbuf[sg * 3 + 1][c4 * 4];
      q[2] = *(const float4*)&qkbuf[sg * 3 + 2][c4 * 4];
      #pragma unroll
      for (int u = 0; u < 4; ++u)
        #pragma unroll
        for (int i = 0; i < 3; ++i)
          acc[u][i] += f[u].x * q[i].x + f[u].y * q[i].y +
                       f[u].z * q[i].z + f[u].w * q[i].w;
    }
  }

  #pragma unroll
  for (int i = 0; i < 3; ++i) {
    int s = sg * 3 + i;
    float* pp = part + (((size_t)kc * B_ + b) * S_ + s) * M_ + m0 + mg;
    #pragma unroll
    for (int u = 0; u < 4; ++u) pp[16 * u] = acc[u][i];
  }
}

// ---- K3: sum k-split partials over a 512-m segment + segment top-2 candidate.
// block = (b*S+s)*8 + seg; 256 threads, 2 m each.
__global__ __launch_bounds__(256) void reduce_kernel(const float* __restrict__ part,
                                                     float* __restrict__ cand) {
  const int seg = blockIdx.x & 7;
  const int bs = blockIdx.x >> 3;     // b*S + s
  const int tid = threadIdx.x;
  const size_t kstride = (size_t)B_ * S_ * M_;
  const float* p0 = part + (size_t)bs * M_ + seg * 512 + tid * 2;
  float a0 = 0.f, a1 = 0.f;
  #pragma unroll
  for (int kc = 0; kc < KS_; ++kc) {
    float2 v = *(const float2*)(p0 + kc * kstride);
    a0 += v.x; a1 += v.y;
  }
  const int mA = seg * 512 + tid * 2;
  float v1, v2; int i1, i2;
  if (better(a0, mA, a1, mA + 1)) { v1 = a0; i1 = mA; v2 = a1; i2 = mA + 1; }
  else                            { v1 = a1; i1 = mA + 1; v2 = a0; i2 = mA; }
  #pragma unroll
  for (int off = 1; off < 64; off <<= 1) {
    float ov1 = __shfl_xor(v1, off);
    int   oi1 = __shfl_xor(i1, off);
    float ov2 = __shfl_xor(v2, off);
    int   oi2 = __shfl_xor(i2, off);
    merge2(v1, i1, v2, i2, ov1, oi1, ov2, oi2);
  }
  __shared__ float cbuf[4][4];
  const int w = tid >> 6, lane = tid & 63;
  if (lane == 0) {
    cbuf[w][0] = v1; ((int*)cbuf[w])[1] = i1;
    cbuf[w][2] = v2; ((int*)cbuf[w])[3] = i2;
  }
  __syncthreads();
  if (tid == 0) {
    for (int ww = 1; ww < 4; ++ww)
      merge2(v1, i1, v2, i2, cbuf[ww][0], ((int*)cbuf[ww])[1],
             cbuf[ww][2], ((int*)cbuf[ww])[3]);
    ((float4*)cand)[blockIdx.x] =
        make_float4(v1, __int_as_float(i1), v2, __int_as_float(i2));
  }
}

// ---- K4: merge 8 candidates -> top-2 + softmax; v-projection; token+feature scatter.
// block = (b,s), s = t*H_+h.
__global__ __launch_bounds__(256) void gather_kernel(const float* __restrict__ x,
    const float* __restrict__ kv_w, const float* __restrict__ experts_w,
    const float* __restrict__ cand, float* __restrict__ out) {
  const int h = blockIdx.x % H_;
  const int t = (blockIdx.x / H_) % T_;
  const int b = blockIdx.x / S_;
  const int tid = threadIdx.x;

  __shared__ float f0[C_], f1[C_], fc[C_], red[256];
  __shared__ float attnh[D_];
  __shared__ float sel[4];

  // --- stage 1: merge the 8 segment candidates ---
  if (tid < 8) {
    float4 cv = ((const float4*)cand)[blockIdx.x * 8 + tid];
    float v1 = cv.x, v2 = cv.z;
    int i1 = __float_as_int(cv.y), i2 = __float_as_int(cv.w);
    #pragma unroll
    for (int off = 1; off < 8; off <<= 1) {
      float ov1 = __shfl_xor(v1, off);
      int   oi1 = __shfl_xor(i1, off);
      float ov2 = __shfl_xor(v2, off);
      int   oi2 = __shfl_xor(i2, off);
      merge2(v1, i1, v2, i2, ov1, oi1, ov2, oi2);
    }
    if (tid == 0) {
      float w1 = 1.f / (1.f + expf(v2 - v1));
      ((int*)sel)[0] = i1; ((int*)sel)[1] = i2;
      sel[2] = w1; sel[3] = 1.f - w1;
    }
  }
  __syncthreads();
  const int i1 = ((const int*)sel)[0];
  const int i2 = ((const int*)sel)[1];
  const float w1 = sel[2], w2 = sel[3];

  // --- stage 2: load selected feature rows ---
  const float* r0 = x + ((size_t)b * N_ + T_ + i1) * C_;
  const float* r1 = x + ((size_t)b * N_ + T_ + i2) * C_;
  for (int i = tid; i < C_; i += 256) {
    float a = r0[i], bb = r1[i];
    f0[i] = a; f1[i] = bb; fc[i] = w1 * a + w2 * bb;
  }
  __syncthreads();

  // --- stage 3: v-projection on combined row -> attnh[64] ---
  const int j = tid & 63, pt = tid >> 6;
  {
    const float* kr = kv_w + ((size_t)(C_ + h * D_ + j)) * C_ + pt * 192;
    float a = 0.f;
    for (int c = 0; c < 192; ++c) a += fc[pt * 192 + c] * kr[c];
    red[tid] = a;
  }
  __syncthreads();
  if (tid < 64)
    attnh[tid] = red[tid] + red[tid + 64] + red[tid + 128] + red[tid + 192];
  __syncthreads();

  // --- stage 4: token + feature scatter (shared experts_w slice) ---
  const size_t ot = ((size_t)b * N_ + t) * C_;
  const size_t o0 = ((size_t)b * N_ + T_ + i1) * C_;
  const size_t o1 = ((size_t)b * N_ + T_ + i2) * C_;
  for (int o = tid; o < C_; o += 256) {
    const float* er = experts_w + ((size_t)t * C_ + o) * C_ + h * D_;
    float at = 0.f, a0 = 0.f, a1 = 0.f;
    #pragma unroll 8
    for (int c = 0; c < D_; ++c) {
      float e = er[c];
      at += e * attnh[c];
      a0 += e * f0[h * D_ + c];
      a1 += e * f1[h * D_ + c];
    }
    atomicAdd(&out[ot + o], at);
    atomicAdd(&out[o0 + o], w1 * a0);
    atomicAdd(&out[o1 + o], w2 * a1);
  }
}

extern "C" void kernel_launch(void* const* d_in, const int* in_sizes, int n_in,
                              void* d_out, int out_size, void* d_ws, size_t ws_size,
                              hipStream_t stream) {
  const float* x         = (const float*)d_in[0];
  const float* qs_w      = (const float*)d_in[1];
  const float* kv_w      = (const float*)d_in[2];
  const float* experts_w = (const float*)d_in[3];
  float* out = (float*)d_out;

  float* ws   = (float*)d_ws;
  float* qk   = ws;                                  // B*S*C     = 73728 floats
  float* part = qk + (size_t)B_ * S_ * C_;           // KS*B*S*M  = 2359296
  float* cand = part + (size_t)KS_ * B_ * S_ * M_;   // B*S*SEG*4 = 3072

  hipLaunchKernelGGL(qkzero_kernel, dim3(GRID_),          dim3(256), 0, stream, x, qs_w, kv_w, qk, out);
  hipLaunchKernelGGL(score_kernel,  dim3(B_ * 64, KS_),   dim3(256), 0, stream, x, qk, part);
  hipLaunchKernelGGL(reduce_kernel, dim3(B_ * S_ * SEG_), dim3(256), 0, stream, part, cand);
  hipLaunchKernelGGL(gather_kernel, dim3(B_ * S_),        dim3(256), 0, stream, x, kv_w, experts_w, cand, out);
}